// Round 2
// baseline (120.195 us; speedup 1.0000x reference)
//
#include <hip/hip_runtime.h>
#include <math.h>

// Problem constants (fixed by the reference).
#define B_ 256
#define J_ 10
#define I_ 1152
#define N_ 16
#define C_ 3      // i-chunks per batch element (grid.x) -> 768 blocks = 3/CU
#define IPC 384   // i per chunk
#define STEPS 6   // 64 i-rows per step

__device__ __forceinline__ float4 ld4(const float* p) {
  return *(const float4*)p;
}

__device__ __forceinline__ float squash16(float s) {
  // s is one component; 16 components live in a 16-lane group (n = lane&15).
  float sq = s * s;
  sq += __shfl_xor(sq, 1);
  sq += __shfl_xor(sq, 2);
  sq += __shfl_xor(sq, 4);
  sq += __shfl_xor(sq, 8);
  return (sq / (1.f + sq)) * s * rsqrtf(sq + 1e-8f);
}

// One streaming pass over u_hat. Output P[chunk][b][j][n] (partials over the
// chunk's i-range).
// MODE 0: c = 1 (plain sum over i)                  -> P = partial S0
// MODE 1: prologue w=v0=squash(S0/J+bias); c=softmax_j(u.w)        (iter 1)
// MODE 2: prologue w=v0+v1, mask mv from threshold; c=softmax(u.w+mv) (iter 2)
template <int MODE>
__global__ __launch_bounds__(256, 3) void pass_kernel(
    const float* __restrict__ u, const float* __restrict__ P0,
    const float* __restrict__ P1, const float* __restrict__ bias,
    float* __restrict__ Pout, float* __restrict__ mvOut) {
  const int tid = threadIdx.x;
  const int q = tid & 3;    // n-quad (float4 of the 16 pose dims)
  const int il = tid >> 2;  // local i row 0..63
  const int chunk = blockIdx.x;
  const int b = blockIdx.y;

  __shared__ float wsh[J_ * N_];
  __shared__ float avg[J_];
  __shared__ float thr_s;

  float4 wq[J_];
  float mvj[J_];

  if (MODE == 1) {
    if (tid < J_ * N_) {
      const int j = tid >> 4, n = tid & 15;
      float s = 0.f;
      for (int c = 0; c < C_; ++c) s += P0[((c * B_ + b) * J_ + j) * N_ + n];
      s = s * (1.f / (float)J_) + bias[j * N_ + n];
      wsh[tid] = squash16(s);
    }
    __syncthreads();
#pragma unroll
    for (int j = 0; j < J_; ++j) {
      wq[j] = ld4(&wsh[j * N_ + q * 4]);
      mvj[j] = 0.f;
    }
  } else if (MODE == 2) {
    if (tid < J_ * N_) {
      const int j = tid >> 4, n = tid & 15;
      float S0 = 0.f;
      for (int c = 0; c < C_; ++c) S0 += P0[((c * B_ + b) * J_ + j) * N_ + n];
      const float bi = bias[j * N_ + n];
      const float v0 = squash16(S0 * (1.f / (float)J_) + bi);
      float s1 = bi;
      for (int c = 0; c < C_; ++c) s1 += P1[((c * B_ + b) * J_ + j) * N_ + n];
      const float v1 = squash16(s1);
      const float w2 = v0 + v1;
      wsh[tid] = w2;
      float pa = S0 * w2;
      pa += __shfl_xor(pa, 1);
      pa += __shfl_xor(pa, 2);
      pa += __shfl_xor(pa, 4);
      pa += __shfl_xor(pa, 8);
      if (n == 0) avg[j] = pa * (1.f / (float)I_);
    }
    __syncthreads();
    if (tid == 0) {
      float a = avg[0];
      for (int jj = 1; jj < J_; ++jj) a = fmaxf(a, avg[jj]);
      float se = 0.f;
      for (int jj = 0; jj < J_; ++jj) se += expf(avg[jj] - a);
      thr_s = logf(0.1f) + a + logf(se);
    }
    __syncthreads();
#pragma unroll
    for (int j = 0; j < J_; ++j) {
      wq[j] = ld4(&wsh[j * N_ + q * 4]);
      mvj[j] = (avg[j] < thr_s) ? -1e30f : 0.f;
    }
    if (chunk == 0 && tid < J_)
      mvOut[b * J_ + tid] = (avg[tid] < thr_s) ? -1e30f : 0.f;
  }

  float4 acc[J_];
#pragma unroll
  for (int j = 0; j < J_; ++j) acc[j] = make_float4(0.f, 0.f, 0.f, 0.f);

  const size_t ubase = (size_t)b * J_ * I_ * N_;
  for (int p = 0; p < STEPS; ++p) {
    const int i = chunk * IPC + p * 64 + il;
    float4 uj[J_];
#pragma unroll
    for (int j = 0; j < J_; ++j)
      uj[j] = ld4(&u[ubase + ((size_t)j * I_ + i) * N_ + q * 4]);

    if (MODE == 0) {
#pragma unroll
      for (int j = 0; j < J_; ++j) {
        acc[j].x += uj[j].x;
        acc[j].y += uj[j].y;
        acc[j].z += uj[j].z;
        acc[j].w += uj[j].w;
      }
    } else {
      float d[J_];
#pragma unroll
      for (int j = 0; j < J_; ++j) {
        float t = uj[j].x * wq[j].x + uj[j].y * wq[j].y + uj[j].z * wq[j].z +
                  uj[j].w * wq[j].w;
        // sum the 4 n-quads (lanes differing in bits 0..1) -> full 16-dot
        t += __shfl_xor(t, 1);
        t += __shfl_xor(t, 2);
        d[j] = t + mvj[j];
      }
      float m = d[0];
#pragma unroll
      for (int j = 1; j < J_; ++j) m = fmaxf(m, d[j]);
      float se = 0.f;
#pragma unroll
      for (int j = 0; j < J_; ++j) {
        d[j] = __expf(d[j] - m);
        se += d[j];
      }
      const float inv = 1.f / se;
#pragma unroll
      for (int j = 0; j < J_; ++j) {
        const float c = d[j] * inv;
        acc[j].x = fmaf(c, uj[j].x, acc[j].x);
        acc[j].y = fmaf(c, uj[j].y, acc[j].y);
        acc[j].z = fmaf(c, uj[j].z, acc[j].z);
        acc[j].w = fmaf(c, uj[j].w, acc[j].w);
      }
    }
  }

  // Reduce over i within the workgroup.
  __shared__ float red[J_ * 64];
  const int lane = tid & 63;
  const int wv = tid >> 6;
#pragma unroll
  for (int j = 0; j < J_; ++j) {
    float4 a = acc[j];
#pragma unroll
    for (int off = 4; off < 64; off <<= 1) {
      a.x += __shfl_xor(a.x, off);
      a.y += __shfl_xor(a.y, off);
      a.z += __shfl_xor(a.z, off);
      a.w += __shfl_xor(a.w, off);
    }
    if (lane < 4) {  // lane == q for lanes 0..3
      red[j * 64 + wv * 16 + lane * 4 + 0] = a.x;
      red[j * 64 + wv * 16 + lane * 4 + 1] = a.y;
      red[j * 64 + wv * 16 + lane * 4 + 2] = a.z;
      red[j * 64 + wv * 16 + lane * 4 + 3] = a.w;
    }
  }
  __syncthreads();
  if (tid < J_ * N_) {
    const int j = tid >> 4, n = tid & 15;
    const float s = red[j * 64 + 0 + n] + red[j * 64 + 16 + n] +
                    red[j * 64 + 32 + n] + red[j * 64 + 48 + n];
    Pout[((chunk * B_ + b) * J_ + j) * N_ + n] = s;
  }
}

// Final: v2 = squash(s2+bias); out = delete ? 0 : v2.
__global__ __launch_bounds__(192) void finishC(const float* __restrict__ P2,
                                               const float* __restrict__ bias,
                                               const float* __restrict__ mv,
                                               float* __restrict__ out) {
  const int b = blockIdx.x, t = threadIdx.x;
  if (t < J_ * N_) {
    const int j = t >> 4, n = t & 15;
    float s = bias[j * N_ + n];
    for (int c = 0; c < C_; ++c) s += P2[((c * B_ + b) * J_ + j) * N_ + n];
    const float v2 = squash16(s);
    const bool del = mv[b * J_ + j] < -1e29f;
    out[(b * J_ + j) * N_ + n] = del ? 0.f : v2;
  }
}

extern "C" void kernel_launch(void* const* d_in, const int* in_sizes, int n_in,
                              void* d_out, int out_size, void* d_ws,
                              size_t ws_size, hipStream_t stream) {
  const float* u = (const float*)d_in[0];     // [B,J,I,N]
  const float* bias = (const float*)d_in[1];  // [J,N]
  // d_in[2] = iters (always 3; structure hardcoded)
  float* ws = (float*)d_ws;
  const size_t psz = (size_t)C_ * B_ * J_ * N_;
  float* P0 = ws;        // partial S0 (kept; needed for threshold)
  float* P1 = P0 + psz;  // partial s from iter 1
  float* P2 = P1 + psz;  // partial s from iter 2
  float* mv = P2 + psz;  // per-(b,j) additive mask
  float* out = (float*)d_out;

  dim3 gp(C_, B_);
  // iter 0: S0 = sum_i u
  hipLaunchKernelGGL((pass_kernel<0>), gp, dim3(256), 0, stream, u,
                     (const float*)nullptr, (const float*)nullptr, bias, P0,
                     (float*)nullptr);
  // iter 1: prologue v0; c = softmax_j(u.v0); P1 = partial s1
  hipLaunchKernelGGL((pass_kernel<1>), gp, dim3(256), 0, stream, u, P0,
                     (const float*)nullptr, bias, P1, (float*)nullptr);
  // iter 2: prologue w=v0+v1 + sparsify mask; c = softmax(u.w + mv); P2
  hipLaunchKernelGGL((pass_kernel<2>), gp, dim3(256), 0, stream, u, P0, P1,
                     bias, P2, mv);
  finishC<<<B_, 192, 0, stream>>>(P2, bias, mv, out);
}

// Round 4
// 108.485 us; speedup vs baseline: 1.1079x; 1.1079x over previous
//
#include <hip/hip_runtime.h>
#include <math.h>

// Problem constants (fixed by the reference).
#define B_ 256
#define J_ 10
#define I_ 1152
#define N_ 16
#define C_ 6      // i-chunks per batch element (grid.x) -> 1536 blocks
#define IPC 192   // i per chunk
#define STEPS 3   // 64 i-rows per step

__device__ __forceinline__ float4 ld4(const float* p) {
  return *(const float4*)p;
}

__device__ __forceinline__ float squash16(float s) {
  // 16 pose components live in a 16-lane group (n = lane&15).
  float sq = s * s;
  sq += __shfl_xor(sq, 1);
  sq += __shfl_xor(sq, 2);
  sq += __shfl_xor(sq, 4);
  sq += __shfl_xor(sq, 8);
  return (sq / (1.f + sq)) * s * rsqrtf(sq + 1e-8f);
}

// One streaming pass over u_hat. Output P[chunk][b][j][n] (partials over the
// chunk's i-range).
// MODE 0: c = 1 (plain sum over i)                  -> P = partial S0
// MODE 1: prologue w=v0=squash(S0/J+bias); c=softmax_j(u.w)        (iter 1)
// MODE 2: prologue w=v0+v1, mask mv from threshold; c=softmax(u.w+mv) (iter 2)
template <int MODE>
__global__ __launch_bounds__(256) void pass_kernel(
    const float* __restrict__ u, const float* __restrict__ P0,
    const float* __restrict__ P1, const float* __restrict__ bias,
    float* __restrict__ Pout, float* __restrict__ mvOut) {
  const int tid = threadIdx.x;
  const int q = tid & 3;    // n-quad (float4 of the 16 pose dims)
  const int il = tid >> 2;  // local i row 0..63
  const int chunk = blockIdx.x;
  const int b = blockIdx.y;

  __shared__ float wsh[J_ * N_];
  __shared__ float avg[J_];
  __shared__ float thr_s;

  float4 wq[J_];
  float mvj[J_];

  if (MODE == 1) {
    if (tid < J_ * N_) {
      const int j = tid >> 4, n = tid & 15;
      float s = 0.f;
      for (int c = 0; c < C_; ++c) s += P0[((c * B_ + b) * J_ + j) * N_ + n];
      s = s * (1.f / (float)J_) + bias[j * N_ + n];
      wsh[tid] = squash16(s);
    }
    __syncthreads();
#pragma unroll
    for (int j = 0; j < J_; ++j) {
      wq[j] = ld4(&wsh[j * N_ + q * 4]);
      mvj[j] = 0.f;
    }
  } else if (MODE == 2) {
    if (tid < J_ * N_) {
      const int j = tid >> 4, n = tid & 15;
      float S0 = 0.f;
      for (int c = 0; c < C_; ++c) S0 += P0[((c * B_ + b) * J_ + j) * N_ + n];
      const float bi = bias[j * N_ + n];
      const float v0 = squash16(S0 * (1.f / (float)J_) + bi);
      float s1 = bi;
      for (int c = 0; c < C_; ++c) s1 += P1[((c * B_ + b) * J_ + j) * N_ + n];
      const float v1 = squash16(s1);
      const float w2 = v0 + v1;
      wsh[tid] = w2;
      float pa = S0 * w2;
      pa += __shfl_xor(pa, 1);
      pa += __shfl_xor(pa, 2);
      pa += __shfl_xor(pa, 4);
      pa += __shfl_xor(pa, 8);
      if (n == 0) avg[j] = pa * (1.f / (float)I_);
    }
    __syncthreads();
    if (tid == 0) {
      float a = avg[0];
      for (int jj = 1; jj < J_; ++jj) a = fmaxf(a, avg[jj]);
      float se = 0.f;
      for (int jj = 0; jj < J_; ++jj) se += expf(avg[jj] - a);
      thr_s = logf(0.1f) + a + logf(se);
    }
    __syncthreads();
#pragma unroll
    for (int j = 0; j < J_; ++j) {
      wq[j] = ld4(&wsh[j * N_ + q * 4]);
      mvj[j] = (avg[j] < thr_s) ? -1e30f : 0.f;
    }
    if (chunk == 0 && tid < J_)
      mvOut[b * J_ + tid] = (avg[tid] < thr_s) ? -1e30f : 0.f;
  }

  float4 acc[J_];
#pragma unroll
  for (int j = 0; j < J_; ++j) acc[j] = make_float4(0.f, 0.f, 0.f, 0.f);

  const size_t ubase = (size_t)b * J_ * I_ * N_;
  for (int p = 0; p < STEPS; ++p) {
    const int i = chunk * IPC + p * 64 + il;
    float4 uj[J_];
#pragma unroll
    for (int j = 0; j < J_; ++j)
      uj[j] = ld4(&u[ubase + ((size_t)j * I_ + i) * N_ + q * 4]);

    if (MODE == 0) {
#pragma unroll
      for (int j = 0; j < J_; ++j) {
        acc[j].x += uj[j].x;
        acc[j].y += uj[j].y;
        acc[j].z += uj[j].z;
        acc[j].w += uj[j].w;
      }
    } else {
      float d[J_];
#pragma unroll
      for (int j = 0; j < J_; ++j) {
        float t = uj[j].x * wq[j].x + uj[j].y * wq[j].y + uj[j].z * wq[j].z +
                  uj[j].w * wq[j].w;
        t += __shfl_xor(t, 1);  // sum the 4 n-quads -> full 16-dot
        t += __shfl_xor(t, 2);
        d[j] = t + mvj[j];
      }
      float m = d[0];
#pragma unroll
      for (int j = 1; j < J_; ++j) m = fmaxf(m, d[j]);
      float se = 0.f;
#pragma unroll
      for (int j = 0; j < J_; ++j) {
        d[j] = __expf(d[j] - m);
        se += d[j];
      }
      const float inv = 1.f / se;
#pragma unroll
      for (int j = 0; j < J_; ++j) {
        const float c = d[j] * inv;
        acc[j].x = fmaf(c, uj[j].x, acc[j].x);
        acc[j].y = fmaf(c, uj[j].y, acc[j].y);
        acc[j].z = fmaf(c, uj[j].z, acc[j].z);
        acc[j].w = fmaf(c, uj[j].w, acc[j].w);
      }
    }
  }

  // Reduce over i within the workgroup.
  __shared__ float red[J_ * 64];
  const int lane = tid & 63;
  const int wv = tid >> 6;
#pragma unroll
  for (int j = 0; j < J_; ++j) {
    float4 a = acc[j];
#pragma unroll
    for (int off = 4; off < 64; off <<= 1) {
      a.x += __shfl_xor(a.x, off);
      a.y += __shfl_xor(a.y, off);
      a.z += __shfl_xor(a.z, off);
      a.w += __shfl_xor(a.w, off);
    }
    if (lane < 4) {  // lane == q for lanes 0..3
      red[j * 64 + wv * 16 + lane * 4 + 0] = a.x;
      red[j * 64 + wv * 16 + lane * 4 + 1] = a.y;
      red[j * 64 + wv * 16 + lane * 4 + 2] = a.z;
      red[j * 64 + wv * 16 + lane * 4 + 3] = a.w;
    }
  }
  __syncthreads();
  if (tid < J_ * N_) {
    const int j = tid >> 4, n = tid & 15;
    const float s = red[j * 64 + 0 + n] + red[j * 64 + 16 + n] +
                    red[j * 64 + 32 + n] + red[j * 64 + 48 + n];
    Pout[((chunk * B_ + b) * J_ + j) * N_ + n] = s;
  }
}

// Final: v2 = squash(s2+bias); out = delete ? 0 : v2.
__global__ __launch_bounds__(192) void finishC(const float* __restrict__ P2,
                                               const float* __restrict__ bias,
                                               const float* __restrict__ mv,
                                               float* __restrict__ out) {
  const int b = blockIdx.x, t = threadIdx.x;
  if (t < J_ * N_) {
    const int j = t >> 4, n = t & 15;
    float s = bias[j * N_ + n];
    for (int c = 0; c < C_; ++c) s += P2[((c * B_ + b) * J_ + j) * N_ + n];
    const float v2 = squash16(s);
    const bool del = mv[b * J_ + j] < -1e29f;
    out[(b * J_ + j) * N_ + n] = del ? 0.f : v2;
  }
}

extern "C" void kernel_launch(void* const* d_in, const int* in_sizes, int n_in,
                              void* d_out, int out_size, void* d_ws,
                              size_t ws_size, hipStream_t stream) {
  const float* u = (const float*)d_in[0];     // [B,J,I,N]
  const float* bias = (const float*)d_in[1];  // [J,N]
  // d_in[2] = iters (always 3; structure hardcoded)
  float* ws = (float*)d_ws;
  const size_t psz = (size_t)C_ * B_ * J_ * N_;
  float* P0 = ws;        // partial S0 (kept; needed for threshold)
  float* P1 = P0 + psz;  // partial s from iter 1
  float* P2 = P1 + psz;  // partial s from iter 2
  float* mv = P2 + psz;  // per-(b,j) additive mask
  float* out = (float*)d_out;

  dim3 gp(C_, B_);
  // iter 0: S0 = sum_i u
  hipLaunchKernelGGL((pass_kernel<0>), gp, dim3(256), 0, stream, u,
                     (const float*)nullptr, (const float*)nullptr, bias, P0,
                     (float*)nullptr);
  // iter 1: prologue v0; c = softmax_j(u.v0); P1 = partial s1
  hipLaunchKernelGGL((pass_kernel<1>), gp, dim3(256), 0, stream, u, P0,
                     (const float*)nullptr, bias, P1, (float*)nullptr);
  // iter 2: prologue w=v0+v1 + sparsify mask; c = softmax(u.w + mv); P2
  hipLaunchKernelGGL((pass_kernel<2>), gp, dim3(256), 0, stream, u, P0, P1,
                     bias, P2, mv);
  finishC<<<B_, 192, 0, stream>>>(P2, bias, mv, out);
}

// Round 5
// 102.932 us; speedup vs baseline: 1.1677x; 1.0540x over previous
//
#include <hip/hip_runtime.h>
#include <math.h>

// Problem constants (fixed by the reference).
#define B_ 256
#define J_ 10
#define I_ 1152
#define N_ 16
#define TPB 512    // 8 waves; one block per batch element; grid = 256 = 1/CU
#define ROWS 128   // i-rows per step = TPB/4
#define STEPS 9    // I_ / ROWS

__device__ __forceinline__ float4 ld4(const float* p) {
  return *(const float4*)p;
}

__device__ __forceinline__ float squash16(float s) {
  // 16 pose components live in a 16-lane group (n = lane&15).
  float sq = s * s;
  sq += __shfl_xor(sq, 1);
  sq += __shfl_xor(sq, 2);
  sq += __shfl_xor(sq, 4);
  sq += __shfl_xor(sq, 8);
  return (sq / (1.f + sq)) * s * rsqrtf(sq + 1e-8f);
}

// Reduce acc[J] (per-thread float4 over rows x q) into red[J][8][16].
// Ends with __syncthreads(); caller reads via red_sum then must sync again
// before red is reused.
__device__ __forceinline__ void block_reduce(const float4* acc,
                                             float* __restrict__ red,
                                             int tid) {
  const int lane = tid & 63;
  const int wv = tid >> 6;
#pragma unroll
  for (int j = 0; j < J_; ++j) {
    float4 a = acc[j];
#pragma unroll
    for (int off = 4; off < 64; off <<= 1) {
      a.x += __shfl_xor(a.x, off);
      a.y += __shfl_xor(a.y, off);
      a.z += __shfl_xor(a.z, off);
      a.w += __shfl_xor(a.w, off);
    }
    if (lane < 4) {  // lane == q for lanes 0..3
      red[(j * 8 + wv) * 16 + lane * 4 + 0] = a.x;
      red[(j * 8 + wv) * 16 + lane * 4 + 1] = a.y;
      red[(j * 8 + wv) * 16 + lane * 4 + 2] = a.z;
      red[(j * 8 + wv) * 16 + lane * 4 + 3] = a.w;
    }
  }
  __syncthreads();
}

__device__ __forceinline__ float red_sum(const float* __restrict__ red, int j,
                                         int n) {
  float s = 0.f;
#pragma unroll
  for (int w = 0; w < 8; ++w) s += red[(j * 8 + w) * 16 + n];
  return s;
}

// One weighted streaming pass: acc[j] += softmax_j(u.w + mv) * u over rows.
__device__ __forceinline__ void stream_w(const float* __restrict__ u,
                                         size_t ubase, const float4* wq,
                                         const float* mvj, float4* acc, int il,
                                         int q) {
#pragma unroll
  for (int j = 0; j < J_; ++j) acc[j] = make_float4(0.f, 0.f, 0.f, 0.f);
  for (int p = 0; p < STEPS; ++p) {
    const int i = p * ROWS + il;
    float4 uj[J_];
#pragma unroll
    for (int j = 0; j < J_; ++j)
      uj[j] = ld4(&u[ubase + ((size_t)j * I_ + i) * N_ + q * 4]);
    float d[J_];
#pragma unroll
    for (int j = 0; j < J_; ++j) {
      float t = uj[j].x * wq[j].x + uj[j].y * wq[j].y + uj[j].z * wq[j].z +
                uj[j].w * wq[j].w;
      t += __shfl_xor(t, 1);  // sum the 4 n-quads -> full 16-dot
      t += __shfl_xor(t, 2);
      d[j] = t + mvj[j];
    }
    float m = d[0];
#pragma unroll
    for (int j = 1; j < J_; ++j) m = fmaxf(m, d[j]);
    float se = 0.f;
#pragma unroll
    for (int j = 0; j < J_; ++j) {
      d[j] = __expf(d[j] - m);
      se += d[j];
    }
    const float inv = 1.f / se;
#pragma unroll
    for (int j = 0; j < J_; ++j) {
      const float c = d[j] * inv;
      acc[j].x = fmaf(c, uj[j].x, acc[j].x);
      acc[j].y = fmaf(c, uj[j].y, acc[j].y);
      acc[j].z = fmaf(c, uj[j].z, acc[j].z);
      acc[j].w = fmaf(c, uj[j].w, acc[j].w);
    }
  }
}

__global__ __launch_bounds__(TPB, 2) void routing_one(
    const float* __restrict__ u, const float* __restrict__ bias,
    float* __restrict__ out) {
  const int tid = threadIdx.x;
  const int q = tid & 3;    // n-quad
  const int il = tid >> 2;  // local i row 0..127
  const int b = blockIdx.x;
  const size_t ubase = (size_t)b * J_ * I_ * N_;

  __shared__ float red[J_ * 8 * 16];
  __shared__ float wsh[J_ * N_];   // current w (v0, then v0+v1)
  __shared__ float v0sh[J_ * N_];  // v0
  __shared__ float S0sh[J_ * N_];  // S0 = sum_i u
  __shared__ float avg[J_];
  __shared__ float thr_s;

  // ---- iter 0: S0 = sum_i u ; v0 = squash(S0/J + bias) -------------------
  {
    float4 acc[J_];
#pragma unroll
    for (int j = 0; j < J_; ++j) acc[j] = make_float4(0.f, 0.f, 0.f, 0.f);
    for (int p = 0; p < STEPS; ++p) {
      const int i = p * ROWS + il;
#pragma unroll
      for (int j = 0; j < J_; ++j) {
        const float4 uj = ld4(&u[ubase + ((size_t)j * I_ + i) * N_ + q * 4]);
        acc[j].x += uj.x;
        acc[j].y += uj.y;
        acc[j].z += uj.z;
        acc[j].w += uj.w;
      }
    }
    block_reduce(acc, red, tid);
  }
  if (tid < J_ * N_) {
    const int j = tid >> 4, n = tid & 15;
    const float S0 = red_sum(red, j, n);
    S0sh[tid] = S0;
    const float s = S0 * (1.f / (float)J_) + bias[j * N_ + n];
    const float v0 = squash16(s);
    v0sh[tid] = v0;
    wsh[tid] = v0;
  }
  __syncthreads();

  float4 wq[J_];
  float mvj[J_];
#pragma unroll
  for (int j = 0; j < J_; ++j) {
    wq[j] = ld4(&wsh[j * N_ + q * 4]);
    mvj[j] = 0.f;
  }

  // ---- iter 1: c = softmax_j(u.v0); v1 = squash(s1+bias); threshold ------
  {
    float4 acc[J_];
    stream_w(u, ubase, wq, mvj, acc, il, q);
    block_reduce(acc, red, tid);
  }
  if (tid < J_ * N_) {
    const int j = tid >> 4, n = tid & 15;
    const float s1 = red_sum(red, j, n) + bias[j * N_ + n];
    const float v1 = squash16(s1);
    const float w2 = v0sh[tid] + v1;
    wsh[tid] = w2;
    float pa = S0sh[tid] * w2;
    pa += __shfl_xor(pa, 1);
    pa += __shfl_xor(pa, 2);
    pa += __shfl_xor(pa, 4);
    pa += __shfl_xor(pa, 8);
    if (n == 0) avg[j] = pa * (1.f / (float)I_);
  }
  __syncthreads();
  if (tid == 0) {
    float a = avg[0];
    for (int jj = 1; jj < J_; ++jj) a = fmaxf(a, avg[jj]);
    float se = 0.f;
    for (int jj = 0; jj < J_; ++jj) se += expf(avg[jj] - a);
    thr_s = logf(0.1f) + a + logf(se);
  }
  __syncthreads();
#pragma unroll
  for (int j = 0; j < J_; ++j) {
    wq[j] = ld4(&wsh[j * N_ + q * 4]);
    mvj[j] = (avg[j] < thr_s) ? -1e30f : 0.f;
  }

  // ---- iter 2: c = softmax_j(u.w + mv); out = del ? 0 : squash(s2) -------
  {
    float4 acc[J_];
    stream_w(u, ubase, wq, mvj, acc, il, q);
    block_reduce(acc, red, tid);
  }
  if (tid < J_ * N_) {
    const int j = tid >> 4, n = tid & 15;
    const float s2 = red_sum(red, j, n) + bias[j * N_ + n];
    const float v2 = squash16(s2);
    const bool del = avg[j] < thr_s;
    out[(b * J_ + j) * N_ + n] = del ? 0.f : v2;
  }
}

extern "C" void kernel_launch(void* const* d_in, const int* in_sizes, int n_in,
                              void* d_out, int out_size, void* d_ws,
                              size_t ws_size, hipStream_t stream) {
  const float* u = (const float*)d_in[0];     // [B,J,I,N]
  const float* bias = (const float*)d_in[1];  // [J,N]
  // d_in[2] = iters (always 3; structure hardcoded)
  float* out = (float*)d_out;
  routing_one<<<B_, TPB, 0, stream>>>(u, bias, out);
}